// Round 12
// baseline (6086.036 us; speedup 1.0000x reference)
//
#include <hip/hip_runtime.h>
#include <hip/hip_bf16.h>
#include <math.h>

// Problem constants
constexpr int Bb  = 16;
constexpr int Ss  = 2048;
constexpr int INd = 32;
constexpr int Dd  = 512;
constexpr int FFf = 2048;
constexpr int Ll  = 6;
constexpr int BS  = Bb * Ss;          // 32768 tokens
constexpr float EPSf = 1e-5f;

typedef __attribute__((ext_vector_type(8))) short short8;   // 8 bf16 (4 VGPRs)
typedef __attribute__((ext_vector_type(4))) float f32x4;

__device__ __forceinline__ ushort f2bf(float f) {
    uint u = __float_as_uint(f);
    uint r = (u + 0x7fffu + ((u >> 16) & 1u)) >> 16;        // round-nearest-even
    return (ushort)r;
}

// ---------------------------------------------------------------------------
// fp32 -> bf16 bulk convert (weights, once per launch)
// ---------------------------------------------------------------------------
__global__ __launch_bounds__(256)
void convert_bf16(const float* __restrict__ in, ushort* __restrict__ out, int n4) {
    int i = blockIdx.x * blockDim.x + threadIdx.x;
    int stride = gridDim.x * blockDim.x;
    for (; i < n4; i += stride) {
        float4 v = ((const float4*)in)[i];
        ushort4 o;
        o.x = f2bf(v.x); o.y = f2bf(v.y); o.z = f2bf(v.z); o.w = f2bf(v.w);
        ((ushort4*)out)[i] = o;
    }
}

// ---------------------------------------------------------------------------
// Encoder v2: register-resident enc_w (validated r10: left top-5, ~25us)
// NOTE: reproduces the reference's pe[:x.shape[0]] broadcast (per-BATCH pe row)
// ---------------------------------------------------------------------------
__global__ __launch_bounds__(256)
void encode_kernel(const float* __restrict__ src, const float* __restrict__ pe,
                   const float* __restrict__ ew, const float* __restrict__ eb,
                   float* __restrict__ y) {
    __shared__ float s_src[8][32];
    const int tid = threadIdx.x;
    const int d0  = 2 * tid;                 // dims d0, d0+1
    float w0[32], w1[32];
    #pragma unroll
    for (int k = 0; k < 32; k += 4) {
        float4 a = *(const float4*)(ew + (size_t)d0 * INd + k);
        float4 b = *(const float4*)(ew + (size_t)(d0 + 1) * INd + k);
        w0[k] = a.x; w0[k+1] = a.y; w0[k+2] = a.z; w0[k+3] = a.w;
        w1[k] = b.x; w1[k+1] = b.y; w1[k+2] = b.z; w1[k+3] = b.w;
    }
    const float e0 = eb[d0], e1 = eb[d0 + 1];
    const float sqrtD = 22.62741699796952f;

    for (int t0 = 0; t0 < BS / 2048; t0 += 8) {
        __syncthreads();                     // protect s_src reuse
        {
            const int j = tid >> 5, e = tid & 31;
            const int tok = (int)blockIdx.x + (t0 + j) * 2048;
            s_src[j][e] = src[(size_t)tok * INd + e];
        }
        __syncthreads();
        #pragma unroll
        for (int j = 0; j < 8; ++j) {
            const int tok = (int)blockIdx.x + (t0 + j) * 2048;
            const int b   = tok >> 11;       // batch index
            float a0 = 0.f, a1 = 0.f;
            #pragma unroll
            for (int k = 0; k < 32; ++k) {
                const float sv = s_src[j][k];
                a0 = fmaf(sv, w0[k], a0);
                a1 = fmaf(sv, w1[k], a1);
            }
            const float2 pv = *(const float2*)(pe + (size_t)b * Dd + d0);
            float2 o;
            o.x = (a0 + e0) * sqrtD + pv.x;
            o.y = (a1 + e1) * sqrtD + pv.y;
            *(float2*)(y + (size_t)tok * Dd + d0) = o;
        }
    }
}

// ---------------------------------------------------------------------------
// XCD-aware token-block swizzle (m204 bijective; nb=8192 divisible by 8):
// contiguous 1024-block (4096-token) chunks per XCD so overlapping 7-row
// attention windows hit the same XCD's L2.
// ---------------------------------------------------------------------------
__device__ __forceinline__ int swz_block(int ob, int nb) {
    return (ob & 7) * (nb >> 3) + (ob >> 3);
}

// ---------------------------------------------------------------------------
// Sparse window attention (W=3 -> 7 keys) + residual + LayerNorm1, fused.
// One wave per token. Writes fp32 y (residual stream) AND bf16 ybf (GEMM1 A).
// Used only for layer 0 (input = encode output).
// ---------------------------------------------------------------------------
__global__ __launch_bounds__(256)
void attn_ln_kernel(const float* __restrict__ x, float* __restrict__ y,
                    ushort* __restrict__ ybf,
                    const float* __restrict__ g, const float* __restrict__ bb) {
    const int wv   = threadIdx.x >> 6;
    const int lane = threadIdx.x & 63;
    const int wid  = swz_block((int)blockIdx.x, (int)gridDim.x) * 4 + wv;
    const int b    = wid >> 11;
    const int s    = wid & (Ss - 1);
    const float* base = x + (size_t)b * Ss * Dd;

    float rows[7][8];
    #pragma unroll
    for (int o = 0; o < 7; ++o) {
        int sp = s + o - 3;
        int sc = sp < 0 ? 0 : (sp > Ss - 1 ? Ss - 1 : sp);
        const float* r = base + (size_t)sc * Dd;
        float4 v0 = *(const float4*)(r + lane * 4);
        float4 v1 = *(const float4*)(r + 256 + lane * 4);
        rows[o][0] = v0.x; rows[o][1] = v0.y; rows[o][2] = v0.z; rows[o][3] = v0.w;
        rows[o][4] = v1.x; rows[o][5] = v1.y; rows[o][6] = v1.z; rows[o][7] = v1.w;
    }

    const float scale = 0.04419417382415922f;   // 1/sqrt(512)
    float score[7];
    #pragma unroll
    for (int o = 0; o < 7; ++o) {
        float p = 0.f;
        #pragma unroll
        for (int j = 0; j < 8; ++j) p = fmaf(rows[3][j], rows[o][j], p);
        #pragma unroll
        for (int m = 1; m < 64; m <<= 1) p += __shfl_xor(p, m, 64);
        int sp = s + o - 3;
        score[o] = (sp >= 0 && sp < Ss) ? p * scale : -1e9f;
    }
    float mx = score[0];
    #pragma unroll
    for (int o = 1; o < 7; ++o) mx = fmaxf(mx, score[o]);
    float w[7], wsum = 0.f;
    #pragma unroll
    for (int o = 0; o < 7; ++o) { w[o] = __expf(score[o] - mx); wsum += w[o]; }
    const float inv = 1.f / wsum;
    #pragma unroll
    for (int o = 0; o < 7; ++o) w[o] *= inv;

    float r2[8];
    #pragma unroll
    for (int j = 0; j < 8; ++j) {
        float acc = rows[3][j];                 // residual (pre-LN x)
        #pragma unroll
        for (int o = 0; o < 7; ++o) acc = fmaf(w[o], rows[o][j], acc);
        r2[j] = acc;
    }

    // LayerNorm over 512
    float sm = 0.f, sq = 0.f;
    #pragma unroll
    for (int j = 0; j < 8; ++j) { sm += r2[j]; sq = fmaf(r2[j], r2[j], sq); }
    #pragma unroll
    for (int m = 1; m < 64; m <<= 1) {
        sm += __shfl_xor(sm, m, 64);
        sq += __shfl_xor(sq, m, 64);
    }
    const float mu   = sm * (1.f / Dd);
    const float var  = sq * (1.f / Dd) - mu * mu;
    const float rstd = rsqrtf(var + EPSf);

    const size_t ob = (size_t)wid * Dd;
    float4 g0 = *(const float4*)(g  + lane * 4);
    float4 b0 = *(const float4*)(bb + lane * 4);
    float4 g1 = *(const float4*)(g  + 256 + lane * 4);
    float4 b1 = *(const float4*)(bb + 256 + lane * 4);
    float4 o0, o1;
    o0.x = (r2[0] - mu) * rstd * g0.x + b0.x;
    o0.y = (r2[1] - mu) * rstd * g0.y + b0.y;
    o0.z = (r2[2] - mu) * rstd * g0.z + b0.z;
    o0.w = (r2[3] - mu) * rstd * g0.w + b0.w;
    o1.x = (r2[4] - mu) * rstd * g1.x + b1.x;
    o1.y = (r2[5] - mu) * rstd * g1.y + b1.y;
    o1.z = (r2[6] - mu) * rstd * g1.z + b1.z;
    o1.w = (r2[7] - mu) * rstd * g1.w + b1.w;
    *(float4*)(y + ob + lane * 4)       = o0;
    *(float4*)(y + ob + 256 + lane * 4) = o1;

    ushort4 q0, q1;
    q0.x = f2bf(o0.x); q0.y = f2bf(o0.y); q0.z = f2bf(o0.z); q0.w = f2bf(o0.w);
    q1.x = f2bf(o1.x); q1.y = f2bf(o1.y); q1.z = f2bf(o1.z); q1.w = f2bf(o1.w);
    *(ushort4*)(ybf + ob + lane * 4)       = q0;
    *(ushort4*)(ybf + ob + 256 + lane * 4) = q1;
}

// ---------------------------------------------------------------------------
// FUSED layer tail + next attention (layers 0..4):
//   per window row j: r_j = LN2(xb_j + f_j)   (recomputed per wave, bit-
//   identical to the old add_ln: same lane layout + shfl tree)
//   then window attention over r_* + residual + LN1 -> y fp32 + ybf bf16.
// Saves materializing the post-FFN stream (xA) entirely: 128MB traffic +
// one dispatch per layer.  y MUST be a different buffer than xb (ping-pong)
// because neighbor blocks still read xb.
// ---------------------------------------------------------------------------
__global__ __launch_bounds__(256)
void fused_tail_attn_kernel(const float* __restrict__ xb, const float* __restrict__ ff,
                            const float* __restrict__ g2, const float* __restrict__ b2,
                            const float* __restrict__ g1, const float* __restrict__ b1,
                            float* __restrict__ y, ushort* __restrict__ ybf) {
    const int wv   = threadIdx.x >> 6;
    const int lane = threadIdx.x & 63;
    const int wid  = swz_block((int)blockIdx.x, (int)gridDim.x) * 4 + wv;
    const int b    = wid >> 11;
    const int s    = wid & (Ss - 1);
    const size_t roff = (size_t)b * Ss * Dd;

    // LN2 params for this lane's elements (shared across the 7 rows)
    float4 G2a = *(const float4*)(g2 + lane * 4);
    float4 G2b = *(const float4*)(g2 + 256 + lane * 4);
    float4 B2a = *(const float4*)(b2 + lane * 4);
    float4 B2b = *(const float4*)(b2 + 256 + lane * 4);

    float rows[7][8];
    #pragma unroll
    for (int o = 0; o < 7; ++o) {
        int sp = s + o - 3;
        int sc = sp < 0 ? 0 : (sp > Ss - 1 ? Ss - 1 : sp);
        const float* xr = xb + roff + (size_t)sc * Dd;
        const float* fr = ff + roff + (size_t)sc * Dd;
        float4 x0 = *(const float4*)(xr + lane * 4);
        float4 f0 = *(const float4*)(fr + lane * 4);
        float4 x1 = *(const float4*)(xr + 256 + lane * 4);
        float4 f1 = *(const float4*)(fr + 256 + lane * 4);
        float r2[8];
        r2[0] = x0.x + f0.x; r2[1] = x0.y + f0.y; r2[2] = x0.z + f0.z; r2[3] = x0.w + f0.w;
        r2[4] = x1.x + f1.x; r2[5] = x1.y + f1.y; r2[6] = x1.z + f1.z; r2[7] = x1.w + f1.w;

        // LN2 (same op order as add_ln -> bit-identical)
        float sm = 0.f, sq = 0.f;
        #pragma unroll
        for (int j = 0; j < 8; ++j) { sm += r2[j]; sq = fmaf(r2[j], r2[j], sq); }
        #pragma unroll
        for (int m = 1; m < 64; m <<= 1) {
            sm += __shfl_xor(sm, m, 64);
            sq += __shfl_xor(sq, m, 64);
        }
        const float mu   = sm * (1.f / Dd);
        const float var  = sq * (1.f / Dd) - mu * mu;
        const float rstd = rsqrtf(var + EPSf);
        rows[o][0] = (r2[0] - mu) * rstd * G2a.x + B2a.x;
        rows[o][1] = (r2[1] - mu) * rstd * G2a.y + B2a.y;
        rows[o][2] = (r2[2] - mu) * rstd * G2a.z + B2a.z;
        rows[o][3] = (r2[3] - mu) * rstd * G2a.w + B2a.w;
        rows[o][4] = (r2[4] - mu) * rstd * G2b.x + B2b.x;
        rows[o][5] = (r2[5] - mu) * rstd * G2b.y + B2b.y;
        rows[o][6] = (r2[6] - mu) * rstd * G2b.z + B2b.z;
        rows[o][7] = (r2[7] - mu) * rstd * G2b.w + B2b.w;
    }

    const float scale = 0.04419417382415922f;   // 1/sqrt(512)
    float score[7];
    #pragma unroll
    for (int o = 0; o < 7; ++o) {
        float p = 0.f;
        #pragma unroll
        for (int j = 0; j < 8; ++j) p = fmaf(rows[3][j], rows[o][j], p);
        #pragma unroll
        for (int m = 1; m < 64; m <<= 1) p += __shfl_xor(p, m, 64);
        int sp = s + o - 3;
        score[o] = (sp >= 0 && sp < Ss) ? p * scale : -1e9f;
    }
    float mx = score[0];
    #pragma unroll
    for (int o = 1; o < 7; ++o) mx = fmaxf(mx, score[o]);
    float w[7], wsum = 0.f;
    #pragma unroll
    for (int o = 0; o < 7; ++o) { w[o] = __expf(score[o] - mx); wsum += w[o]; }
    const float inv = 1.f / wsum;
    #pragma unroll
    for (int o = 0; o < 7; ++o) w[o] *= inv;

    float r2[8];
    #pragma unroll
    for (int j = 0; j < 8; ++j) {
        float acc = rows[3][j];                 // residual (LN2'd center row)
        #pragma unroll
        for (int o = 0; o < 7; ++o) acc = fmaf(w[o], rows[o][j], acc);
        r2[j] = acc;
    }

    // LayerNorm1 over 512
    float sm = 0.f, sq = 0.f;
    #pragma unroll
    for (int j = 0; j < 8; ++j) { sm += r2[j]; sq = fmaf(r2[j], r2[j], sq); }
    #pragma unroll
    for (int m = 1; m < 64; m <<= 1) {
        sm += __shfl_xor(sm, m, 64);
        sq += __shfl_xor(sq, m, 64);
    }
    const float mu   = sm * (1.f / Dd);
    const float var  = sq * (1.f / Dd) - mu * mu;
    const float rstd = rsqrtf(var + EPSf);

    const size_t ob = (size_t)wid * Dd;
    float4 g0 = *(const float4*)(g1 + lane * 4);
    float4 b0 = *(const float4*)(b1 + lane * 4);
    float4 g1v = *(const float4*)(g1 + 256 + lane * 4);
    float4 b1v = *(const float4*)(b1 + 256 + lane * 4);
    float4 o0, o1;
    o0.x = (r2[0] - mu) * rstd * g0.x + b0.x;
    o0.y = (r2[1] - mu) * rstd * g0.y + b0.y;
    o0.z = (r2[2] - mu) * rstd * g0.z + b0.z;
    o0.w = (r2[3] - mu) * rstd * g0.w + b0.w;
    o1.x = (r2[4] - mu) * rstd * g1v.x + b1v.x;
    o1.y = (r2[5] - mu) * rstd * g1v.y + b1v.y;
    o1.z = (r2[6] - mu) * rstd * g1v.z + b1v.z;
    o1.w = (r2[7] - mu) * rstd * g1v.w + b1v.w;
    *(float4*)(y + ob + lane * 4)       = o0;
    *(float4*)(y + ob + 256 + lane * 4) = o1;

    ushort4 q0, q1;
    q0.x = f2bf(o0.x); q0.y = f2bf(o0.y); q0.z = f2bf(o0.z); q0.w = f2bf(o0.w);
    q1.x = f2bf(o1.x); q1.y = f2bf(o1.y); q1.z = f2bf(o1.z); q1.w = f2bf(o1.w);
    *(ushort4*)(ybf + ob + lane * 4)       = q0;
    *(ushort4*)(ybf + ob + 256 + lane * 4) = q1;
}

// ---------------------------------------------------------------------------
// residual add + LayerNorm:  f <- LN(xres + f) * g + b   (in-place on f)
// Used only for the final layer (decode needs the materialized stream).
// ---------------------------------------------------------------------------
__global__ __launch_bounds__(256)
void add_ln_kernel(const float* __restrict__ xres, float* __restrict__ f,
                   const float* __restrict__ g, const float* __restrict__ bb) {
    const int wv   = threadIdx.x >> 6;
    const int lane = threadIdx.x & 63;
    const int wid  = blockIdx.x * 4 + wv;
    const size_t ob = (size_t)wid * Dd;

    float4 a0 = *(const float4*)(xres + ob + lane * 4);
    float4 f0 = *(const float4*)(f    + ob + lane * 4);
    float4 a1 = *(const float4*)(xres + ob + 256 + lane * 4);
    float4 f1 = *(const float4*)(f    + ob + 256 + lane * 4);
    float r2[8];
    r2[0] = a0.x + f0.x; r2[1] = a0.y + f0.y; r2[2] = a0.z + f0.z; r2[3] = a0.w + f0.w;
    r2[4] = a1.x + f1.x; r2[5] = a1.y + f1.y; r2[6] = a1.z + f1.z; r2[7] = a1.w + f1.w;

    float sm = 0.f, sq = 0.f;
    #pragma unroll
    for (int j = 0; j < 8; ++j) { sm += r2[j]; sq = fmaf(r2[j], r2[j], sq); }
    #pragma unroll
    for (int m = 1; m < 64; m <<= 1) {
        sm += __shfl_xor(sm, m, 64);
        sq += __shfl_xor(sq, m, 64);
    }
    const float mu   = sm * (1.f / Dd);
    const float var  = sq * (1.f / Dd) - mu * mu;
    const float rstd = rsqrtf(var + EPSf);

    float4 g0 = *(const float4*)(g  + lane * 4);
    float4 b0 = *(const float4*)(bb + lane * 4);
    float4 g1 = *(const float4*)(g  + 256 + lane * 4);
    float4 b1 = *(const float4*)(bb + 256 + lane * 4);
    float4 o0, o1;
    o0.x = (r2[0] - mu) * rstd * g0.x + b0.x;
    o0.y = (r2[1] - mu) * rstd * g0.y + b0.y;
    o0.z = (r2[2] - mu) * rstd * g0.z + b0.z;
    o0.w = (r2[3] - mu) * rstd * g0.w + b0.w;
    o1.x = (r2[4] - mu) * rstd * g1.x + b1.x;
    o1.y = (r2[5] - mu) * rstd * g1.y + b1.y;
    o1.z = (r2[6] - mu) * rstd * g1.z + b1.z;
    o1.w = (r2[7] - mu) * rstd * g1.w + b1.w;
    *(float4*)(f + ob + lane * 4)       = o0;
    *(float4*)(f + ob + 256 + lane * 4) = o1;
}

// ---------------------------------------------------------------------------
// bf16 MFMA NT GEMM (m97 structure, 873 TF measured r10 = structure ceiling)
// ---------------------------------------------------------------------------
template<int RELU, int BF16OUT>
__global__ __launch_bounds__(256)
void gemm_bf16(const ushort* __restrict__ A, const ushort* __restrict__ B,
               const float* __restrict__ bias, void* __restrict__ Cout,
               int M, int N, int K) {
    __shared__ ushort As[128 * 32];          // [row][k] bf16, 8KB
    __shared__ ushort Bs[128 * 32];
    const int tid  = threadIdx.x;
    const int wid  = tid >> 6;
    const int lane = tid & 63;
    const int wr   = wid >> 1;               // wave quadrant row (0/1)
    const int wc   = wid & 1;                // wave quadrant col (0/1)

    // ---- XCD-aware bijective swizzle (m204) ----
    const int nwg  = (int)(gridDim.x * gridDim.y);
    const int orig = (int)(blockIdx.y * gridDim.x + blockIdx.x);
    const int q    = nwg >> 3, r = nwg & 7;
    const int xcd  = orig & 7, seq = orig >> 3;
    const int swz  = (xcd < r ? xcd * (q + 1) : r * (q + 1) + (xcd - r) * q) + seq;
    const int bxT  = swz % (int)gridDim.x;   // N-tile (fast dim)
    const int byT  = swz / (int)gridDim.x;   // M-tile
    const size_t bm = (size_t)byT * 128;
    const size_t bn = (size_t)bxT * 128;

    const ushort* gA0 = A + (bm + wid * 32 + (lane >> 2)) * (size_t)K + (lane & 3) * 8;
    const ushort* gA1 = gA0 + (size_t)16 * K;
    const ushort* gB0 = B + (bn + wid * 32 + (lane >> 2)) * (size_t)K + (lane & 3) * 8;
    const ushort* gB1 = gB0 + (size_t)16 * K;
    ushort* lA0 = &As[wid * 1024];
    ushort* lA1 = lA0 + 512;
    ushort* lB0 = &Bs[wid * 1024];
    ushort* lB1 = lB0 + 512;

    const ushort* aPtr = &As[(wr * 64 + (lane & 15)) * 32 + (lane >> 4) * 8];
    const ushort* bPtr = &Bs[(wc * 64 + (lane & 15)) * 32 + (lane >> 4) * 8];

    f32x4 acc[4][4];
    #pragma unroll
    for (int i = 0; i < 4; ++i)
        #pragma unroll
        for (int j = 0; j < 4; ++j) acc[i][j] = (f32x4){0.f, 0.f, 0.f, 0.f};

    #define GLDS(gp, lp) __builtin_amdgcn_global_load_lds( \
        (const __attribute__((address_space(1))) void*)(gp), \
        (__attribute__((address_space(3))) void*)(lp), 16, 0, 0)

    for (int k0 = 0; k0 < K; k0 += 32) {
        GLDS(gA0 + k0, lA0);
        GLDS(gA1 + k0, lA1);
        GLDS(gB0 + k0, lB0);
        GLDS(gB1 + k0, lB1);
        __syncthreads();
        short8 af[4], bf_[4];
        #pragma unroll
        for (int mt = 0; mt < 4; ++mt) af[mt]  = *(const short8*)(aPtr + mt * 512);
        #pragma unroll
        for (int nt = 0; nt < 4; ++nt) bf_[nt] = *(const short8*)(bPtr + nt * 512);
        #pragma unroll
        for (int mt = 0; mt < 4; ++mt)
            #pragma unroll
            for (int nt = 0; nt < 4; ++nt)
                acc[mt][nt] = __builtin_amdgcn_mfma_f32_16x16x32_bf16(
                    af[mt], bf_[nt], acc[mt][nt], 0, 0, 0);
        __syncthreads();
    }
    #undef GLDS

    float* Cf  = (float*)Cout;
    ushort* Cb = (ushort*)Cout;
    #pragma unroll
    for (int nt = 0; nt < 4; ++nt) {
        const int cn = (int)bn + wc * 64 + nt * 16 + (lane & 15);
        const float bv = bias[cn];
        #pragma unroll
        for (int mt = 0; mt < 4; ++mt) {
            const size_t rowb = bm + wr * 64 + mt * 16 + (lane >> 4) * 4;
            #pragma unroll
            for (int rr = 0; rr < 4; ++rr) {
                float v = acc[mt][nt][rr] + bv;
                if (RELU) v = fmaxf(v, 0.f);
                if (BF16OUT) Cb[(rowb + rr) * (size_t)N + cn] = f2bf(v);
                else         Cf[(rowb + rr) * (size_t)N + cn] = v;
            }
        }
    }
}

// ---------------------------------------------------------------------------
// Decoder: out[b] = x[b, S-1, :] . dec_w + dec_b
// ---------------------------------------------------------------------------
__global__ __launch_bounds__(64)
void decode_kernel(const float* __restrict__ x, const float* __restrict__ dw,
                   const float* __restrict__ db, float* __restrict__ out) {
    const int b = blockIdx.x;
    const int lane = threadIdx.x;
    const float* r = x + ((size_t)b * Ss + (Ss - 1)) * Dd;
    float acc = 0.f;
    #pragma unroll
    for (int j = 0; j < 8; ++j) acc = fmaf(r[j*64 + lane], dw[j*64 + lane], acc);
    #pragma unroll
    for (int m = 1; m < 64; m <<= 1) acc += __shfl_xor(acc, m, 64);
    if (lane == 0) out[b] = acc + db[0];
}

// ---------------------------------------------------------------------------
extern "C" void kernel_launch(void* const* d_in, const int* in_sizes, int n_in,
                              void* d_out, int out_size, void* d_ws, size_t ws_size,
                              hipStream_t stream) {
    const float* src   = (const float*)d_in[0];
    const float* pe    = (const float*)d_in[1];
    const float* enc_w = (const float*)d_in[2];
    const float* enc_b = (const float*)d_in[3];
    const float* l1_w  = (const float*)d_in[4];
    const float* l1_b  = (const float*)d_in[5];
    const float* l2_w  = (const float*)d_in[6];
    const float* l2_b  = (const float*)d_in[7];
    const float* n1_g  = (const float*)d_in[8];
    const float* n1_b  = (const float*)d_in[9];
    const float* n2_g  = (const float*)d_in[10];
    const float* n2_b  = (const float*)d_in[11];
    const float* dec_w = (const float*)d_in[12];
    const float* dec_b = (const float*)d_in[13];
    float* out = (float*)d_out;

    // workspace (fixed 248MB): f/xA f32 64MB | xB_a 64MB | xB_b 64MB |
    //   xBbf 32MB | w1bf 12MB | w2bf 12MB | hbf (remainder, chunk-adaptive;
    //   single-pass needs 128MB -> 376MB total).
    // f reuses the encode-output slot: attn_ln(0) consumes it before GEMM2(0)
    // overwrites it; add_ln(5) writes the final stream there for decode.
    const size_t NTOK = (size_t)BS * Dd;          // 16.78M
    float*  fbuf = (float*)d_ws;                  // encode out / FFN out / final
    float*  xBa  = fbuf + NTOK;
    float*  xBb  = xBa + NTOK;
    ushort* xBbf = (ushort*)(xBb + NTOK);
    ushort* w1bf = xBbf + NTOK;
    ushort* w2bf = w1bf + (size_t)Ll * FFf * Dd;
    ushort* hbf  = w2bf + (size_t)Ll * FFf * Dd;

    const size_t fixedBytes = (size_t)((char*)hbf - (char*)d_ws);
    size_t hBytes = ws_size > fixedBytes ? ws_size - fixedBytes : 0;
    int    chunkM = (int)(hBytes / ((size_t)FFf * sizeof(ushort)));
    if (chunkM > BS) chunkM = BS;
    chunkM &= ~127;                      // multiple of the GEMM tile height
    if (chunkM < 128) chunkM = 128;      // last resort: 512KB chunk

    const int wn4 = Ll * FFf * Dd / 4;
    convert_bf16<<<1024, 256, 0, stream>>>(l1_w, w1bf, wn4);
    convert_bf16<<<1024, 256, 0, stream>>>(l2_w, w2bf, wn4);

    encode_kernel<<<2048, 256, 0, stream>>>(src, pe, enc_w, enc_b, fbuf);

    attn_ln_kernel<<<BS / 4, 256, 0, stream>>>(
        fbuf, xBa, xBbf, n1_g, n1_b);            // layer 0 LN1

    float* curXB = xBa;
    float* nxtXB = xBb;
    for (int i = 0; i < Ll; ++i) {
        for (int m0 = 0; m0 < BS; m0 += chunkM) {
            int mh = (BS - m0) < chunkM ? (BS - m0) : chunkM;
            gemm_bf16<1, 1><<<dim3(FFf / 128, mh / 128), 256, 0, stream>>>(
                xBbf + (size_t)m0 * Dd, w1bf + (size_t)i * FFf * Dd,
                l1_b + i * FFf, hbf, mh, FFf, Dd);
            gemm_bf16<0, 0><<<dim3(Dd / 128, mh / 128), 256, 0, stream>>>(
                hbf, w2bf + (size_t)i * Dd * FFf, l2_b + i * Dd,
                fbuf + (size_t)m0 * Dd, mh, Dd, FFf);
        }
        if (i < Ll - 1) {
            fused_tail_attn_kernel<<<BS / 4, 256, 0, stream>>>(
                curXB, fbuf,
                n2_g + i * Dd, n2_b + i * Dd,            // LN2 (layer i)
                n1_g + (i + 1) * Dd, n1_b + (i + 1) * Dd, // LN1 (layer i+1)
                nxtXB, xBbf);
            float* t = curXB; curXB = nxtXB; nxtXB = t;
        } else {
            add_ln_kernel<<<BS / 4, 256, 0, stream>>>(
                curXB, fbuf, n2_g + i * Dd, n2_b + i * Dd);
        }
    }

    decode_kernel<<<Bb, 64, 0, stream>>>(fbuf, dec_w, dec_b, out);
}

// Round 13
// 2106.553 us; speedup vs baseline: 2.8891x; 2.8891x over previous
//
#include <hip/hip_runtime.h>
#include <hip/hip_bf16.h>
#include <math.h>

// Problem constants
constexpr int Bb  = 16;
constexpr int Ss  = 2048;
constexpr int INd = 32;
constexpr int Dd  = 512;
constexpr int FFf = 2048;
constexpr int Ll  = 6;
constexpr int BS  = Bb * Ss;          // 32768 tokens
constexpr float EPSf = 1e-5f;

typedef __attribute__((ext_vector_type(8))) short short8;   // 8 bf16 (4 VGPRs)
typedef __attribute__((ext_vector_type(4))) float f32x4;

__device__ __forceinline__ ushort f2bf(float f) {
    uint u = __float_as_uint(f);
    uint r = (u + 0x7fffu + ((u >> 16) & 1u)) >> 16;        // round-nearest-even
    return (ushort)r;
}
__device__ __forceinline__ float bf2f(ushort u) {
    return __uint_as_float((uint)u << 16);
}

// ---------------------------------------------------------------------------
// fp32 -> bf16 bulk convert (weights, once per launch)
// ---------------------------------------------------------------------------
__global__ __launch_bounds__(256)
void convert_bf16(const float* __restrict__ in, ushort* __restrict__ out, int n4) {
    int i = blockIdx.x * blockDim.x + threadIdx.x;
    int stride = gridDim.x * blockDim.x;
    for (; i < n4; i += stride) {
        float4 v = ((const float4*)in)[i];
        ushort4 o;
        o.x = f2bf(v.x); o.y = f2bf(v.y); o.z = f2bf(v.z); o.w = f2bf(v.w);
        ((ushort4*)out)[i] = o;
    }
}

// ---------------------------------------------------------------------------
// Encoder v2: register-resident enc_w (validated r10)
// NOTE: reproduces the reference's pe[:x.shape[0]] broadcast (per-BATCH pe row)
// ---------------------------------------------------------------------------
__global__ __launch_bounds__(256)
void encode_kernel(const float* __restrict__ src, const float* __restrict__ pe,
                   const float* __restrict__ ew, const float* __restrict__ eb,
                   float* __restrict__ y) {
    __shared__ float s_src[8][32];
    const int tid = threadIdx.x;
    const int d0  = 2 * tid;                 // dims d0, d0+1
    float w0[32], w1[32];
    #pragma unroll
    for (int k = 0; k < 32; k += 4) {
        float4 a = *(const float4*)(ew + (size_t)d0 * INd + k);
        float4 b = *(const float4*)(ew + (size_t)(d0 + 1) * INd + k);
        w0[k] = a.x; w0[k+1] = a.y; w0[k+2] = a.z; w0[k+3] = a.w;
        w1[k] = b.x; w1[k+1] = b.y; w1[k+2] = b.z; w1[k+3] = b.w;
    }
    const float e0 = eb[d0], e1 = eb[d0 + 1];
    const float sqrtD = 22.62741699796952f;

    for (int t0 = 0; t0 < BS / 2048; t0 += 8) {
        __syncthreads();                     // protect s_src reuse
        {
            const int j = tid >> 5, e = tid & 31;
            const int tok = (int)blockIdx.x + (t0 + j) * 2048;
            s_src[j][e] = src[(size_t)tok * INd + e];
        }
        __syncthreads();
        #pragma unroll
        for (int j = 0; j < 8; ++j) {
            const int tok = (int)blockIdx.x + (t0 + j) * 2048;
            const int b   = tok >> 11;       // batch index
            float a0 = 0.f, a1 = 0.f;
            #pragma unroll
            for (int k = 0; k < 32; ++k) {
                const float sv = s_src[j][k];
                a0 = fmaf(sv, w0[k], a0);
                a1 = fmaf(sv, w1[k], a1);
            }
            const float2 pv = *(const float2*)(pe + (size_t)b * Dd + d0);
            float2 o;
            o.x = (a0 + e0) * sqrtD + pv.x;
            o.y = (a1 + e1) * sqrtD + pv.y;
            *(float2*)(y + (size_t)tok * Dd + d0) = o;
        }
    }
}

// ---------------------------------------------------------------------------
// XCD-aware token-block swizzle (m204 bijective; nb=8192 divisible by 8)
// ---------------------------------------------------------------------------
__device__ __forceinline__ int swz_block(int ob, int nb) {
    return (ob & 7) * (nb >> 3) + (ob >> 3);
}

// ---------------------------------------------------------------------------
// Layer-0 attention + LN1: reads fp32 encode output, writes bf16 stream ONLY
// (the fp32 stream copy was redundant: GEMM1 consumed the bf16 copy anyway).
// ---------------------------------------------------------------------------
__global__ __launch_bounds__(256)
void attn_ln_kernel(const float* __restrict__ x, ushort* __restrict__ ybf,
                    const float* __restrict__ g, const float* __restrict__ bb) {
    const int wv   = threadIdx.x >> 6;
    const int lane = threadIdx.x & 63;
    const int wid  = swz_block((int)blockIdx.x, (int)gridDim.x) * 4 + wv;
    const int b    = wid >> 11;
    const int s    = wid & (Ss - 1);
    const float* base = x + (size_t)b * Ss * Dd;

    float rows[7][8];
    #pragma unroll
    for (int o = 0; o < 7; ++o) {
        int sp = s + o - 3;
        int sc = sp < 0 ? 0 : (sp > Ss - 1 ? Ss - 1 : sp);
        const float* r = base + (size_t)sc * Dd;
        float4 v0 = *(const float4*)(r + lane * 4);
        float4 v1 = *(const float4*)(r + 256 + lane * 4);
        rows[o][0] = v0.x; rows[o][1] = v0.y; rows[o][2] = v0.z; rows[o][3] = v0.w;
        rows[o][4] = v1.x; rows[o][5] = v1.y; rows[o][6] = v1.z; rows[o][7] = v1.w;
    }

    const float scale = 0.04419417382415922f;   // 1/sqrt(512)
    float score[7];
    #pragma unroll
    for (int o = 0; o < 7; ++o) {
        float p = 0.f;
        #pragma unroll
        for (int j = 0; j < 8; ++j) p = fmaf(rows[3][j], rows[o][j], p);
        #pragma unroll
        for (int m = 1; m < 64; m <<= 1) p += __shfl_xor(p, m, 64);
        int sp = s + o - 3;
        score[o] = (sp >= 0 && sp < Ss) ? p * scale : -1e9f;
    }
    float mx = score[0];
    #pragma unroll
    for (int o = 1; o < 7; ++o) mx = fmaxf(mx, score[o]);
    float w[7], wsum = 0.f;
    #pragma unroll
    for (int o = 0; o < 7; ++o) { w[o] = __expf(score[o] - mx); wsum += w[o]; }
    const float inv = 1.f / wsum;
    #pragma unroll
    for (int o = 0; o < 7; ++o) w[o] *= inv;

    float r2[8];
    #pragma unroll
    for (int j = 0; j < 8; ++j) {
        float acc = rows[3][j];                 // residual (pre-LN x)
        #pragma unroll
        for (int o = 0; o < 7; ++o) acc = fmaf(w[o], rows[o][j], acc);
        r2[j] = acc;
    }

    float sm = 0.f, sq = 0.f;
    #pragma unroll
    for (int j = 0; j < 8; ++j) { sm += r2[j]; sq = fmaf(r2[j], r2[j], sq); }
    #pragma unroll
    for (int m = 1; m < 64; m <<= 1) {
        sm += __shfl_xor(sm, m, 64);
        sq += __shfl_xor(sq, m, 64);
    }
    const float mu   = sm * (1.f / Dd);
    const float var  = sq * (1.f / Dd) - mu * mu;
    const float rstd = rsqrtf(var + EPSf);

    const size_t ob = (size_t)wid * Dd;
    float4 g0 = *(const float4*)(g  + lane * 4);
    float4 b0 = *(const float4*)(bb + lane * 4);
    float4 g1 = *(const float4*)(g  + 256 + lane * 4);
    float4 b1 = *(const float4*)(bb + 256 + lane * 4);
    ushort4 q0, q1;
    q0.x = f2bf((r2[0] - mu) * rstd * g0.x + b0.x);
    q0.y = f2bf((r2[1] - mu) * rstd * g0.y + b0.y);
    q0.z = f2bf((r2[2] - mu) * rstd * g0.z + b0.z);
    q0.w = f2bf((r2[3] - mu) * rstd * g0.w + b0.w);
    q1.x = f2bf((r2[4] - mu) * rstd * g1.x + b1.x);
    q1.y = f2bf((r2[5] - mu) * rstd * g1.y + b1.y);
    q1.z = f2bf((r2[6] - mu) * rstd * g1.z + b1.z);
    q1.w = f2bf((r2[7] - mu) * rstd * g1.w + b1.w);
    *(ushort4*)(ybf + ob + lane * 4)       = q0;
    *(ushort4*)(ybf + ob + 256 + lane * 4) = q1;
}

// ---------------------------------------------------------------------------
// FUSED layer tail + next attention (layers 0..4):
//   xb stream is bf16 (ping-pong); ff (FFN out) fp32.
//   per row j: r_j = LN2(bf2f(xb_j) + f_j); attention over r_*; +res; LN1
//   -> writes bf16 next-stream only.
// ---------------------------------------------------------------------------
__global__ __launch_bounds__(256)
void fused_tail_attn_kernel(const ushort* __restrict__ xb, const float* __restrict__ ff,
                            const float* __restrict__ g2, const float* __restrict__ b2,
                            const float* __restrict__ g1, const float* __restrict__ b1,
                            ushort* __restrict__ ybf) {
    const int wv   = threadIdx.x >> 6;
    const int lane = threadIdx.x & 63;
    const int wid  = swz_block((int)blockIdx.x, (int)gridDim.x) * 4 + wv;
    const int b    = wid >> 11;
    const int s    = wid & (Ss - 1);
    const size_t roff = (size_t)b * Ss * Dd;

    float4 G2a = *(const float4*)(g2 + lane * 4);
    float4 G2b = *(const float4*)(g2 + 256 + lane * 4);
    float4 B2a = *(const float4*)(b2 + lane * 4);
    float4 B2b = *(const float4*)(b2 + 256 + lane * 4);

    float rows[7][8];
    #pragma unroll
    for (int o = 0; o < 7; ++o) {
        int sp = s + o - 3;
        int sc = sp < 0 ? 0 : (sp > Ss - 1 ? Ss - 1 : sp);
        const ushort* xr = xb + roff + (size_t)sc * Dd;
        const float*  fr = ff + roff + (size_t)sc * Dd;
        ushort4 x0 = *(const ushort4*)(xr + lane * 4);
        float4  f0 = *(const float4*)(fr + lane * 4);
        ushort4 x1 = *(const ushort4*)(xr + 256 + lane * 4);
        float4  f1 = *(const float4*)(fr + 256 + lane * 4);
        float r2[8];
        r2[0] = bf2f(x0.x) + f0.x; r2[1] = bf2f(x0.y) + f0.y;
        r2[2] = bf2f(x0.z) + f0.z; r2[3] = bf2f(x0.w) + f0.w;
        r2[4] = bf2f(x1.x) + f1.x; r2[5] = bf2f(x1.y) + f1.y;
        r2[6] = bf2f(x1.z) + f1.z; r2[7] = bf2f(x1.w) + f1.w;

        float sm = 0.f, sq = 0.f;
        #pragma unroll
        for (int j = 0; j < 8; ++j) { sm += r2[j]; sq = fmaf(r2[j], r2[j], sq); }
        #pragma unroll
        for (int m = 1; m < 64; m <<= 1) {
            sm += __shfl_xor(sm, m, 64);
            sq += __shfl_xor(sq, m, 64);
        }
        const float mu   = sm * (1.f / Dd);
        const float var  = sq * (1.f / Dd) - mu * mu;
        const float rstd = rsqrtf(var + EPSf);
        rows[o][0] = (r2[0] - mu) * rstd * G2a.x + B2a.x;
        rows[o][1] = (r2[1] - mu) * rstd * G2a.y + B2a.y;
        rows[o][2] = (r2[2] - mu) * rstd * G2a.z + B2a.z;
        rows[o][3] = (r2[3] - mu) * rstd * G2a.w + B2a.w;
        rows[o][4] = (r2[4] - mu) * rstd * G2b.x + B2b.x;
        rows[o][5] = (r2[5] - mu) * rstd * G2b.y + B2b.y;
        rows[o][6] = (r2[6] - mu) * rstd * G2b.z + B2b.z;
        rows[o][7] = (r2[7] - mu) * rstd * G2b.w + B2b.w;
    }

    const float scale = 0.04419417382415922f;   // 1/sqrt(512)
    float score[7];
    #pragma unroll
    for (int o = 0; o < 7; ++o) {
        float p = 0.f;
        #pragma unroll
        for (int j = 0; j < 8; ++j) p = fmaf(rows[3][j], rows[o][j], p);
        #pragma unroll
        for (int m = 1; m < 64; m <<= 1) p += __shfl_xor(p, m, 64);
        int sp = s + o - 3;
        score[o] = (sp >= 0 && sp < Ss) ? p * scale : -1e9f;
    }
    float mx = score[0];
    #pragma unroll
    for (int o = 1; o < 7; ++o) mx = fmaxf(mx, score[o]);
    float w[7], wsum = 0.f;
    #pragma unroll
    for (int o = 0; o < 7; ++o) { w[o] = __expf(score[o] - mx); wsum += w[o]; }
    const float inv = 1.f / wsum;
    #pragma unroll
    for (int o = 0; o < 7; ++o) w[o] *= inv;

    float r2[8];
    #pragma unroll
    for (int j = 0; j < 8; ++j) {
        float acc = rows[3][j];                 // residual (LN2'd center row)
        #pragma unroll
        for (int o = 0; o < 7; ++o) acc = fmaf(w[o], rows[o][j], acc);
        r2[j] = acc;
    }

    float sm = 0.f, sq = 0.f;
    #pragma unroll
    for (int j = 0; j < 8; ++j) { sm += r2[j]; sq = fmaf(r2[j], r2[j], sq); }
    #pragma unroll
    for (int m = 1; m < 64; m <<= 1) {
        sm += __shfl_xor(sm, m, 64);
        sq += __shfl_xor(sq, m, 64);
    }
    const float mu   = sm * (1.f / Dd);
    const float var  = sq * (1.f / Dd) - mu * mu;
    const float rstd = rsqrtf(var + EPSf);

    const size_t ob = (size_t)wid * Dd;
    float4 g0 = *(const float4*)(g1 + lane * 4);
    float4 b0 = *(const float4*)(b1 + lane * 4);
    float4 g1v = *(const float4*)(g1 + 256 + lane * 4);
    float4 b1v = *(const float4*)(b1 + 256 + lane * 4);
    ushort4 q0, q1;
    q0.x = f2bf((r2[0] - mu) * rstd * g0.x + b0.x);
    q0.y = f2bf((r2[1] - mu) * rstd * g0.y + b0.y);
    q0.z = f2bf((r2[2] - mu) * rstd * g0.z + b0.z);
    q0.w = f2bf((r2[3] - mu) * rstd * g0.w + b0.w);
    q1.x = f2bf((r2[4] - mu) * rstd * g1v.x + b1v.x);
    q1.y = f2bf((r2[5] - mu) * rstd * g1v.y + b1v.y);
    q1.z = f2bf((r2[6] - mu) * rstd * g1v.z + b1v.z);
    q1.w = f2bf((r2[7] - mu) * rstd * g1v.w + b1v.w);
    *(ushort4*)(ybf + ob + lane * 4)       = q0;
    *(ushort4*)(ybf + ob + 256 + lane * 4) = q1;
}

// ---------------------------------------------------------------------------
// Final-layer residual add + LN2: f <- LN(bf2f(xres) + f) * g + b  (in-place
// on fp32 f; decode reads it afterwards).
// ---------------------------------------------------------------------------
__global__ __launch_bounds__(256)
void add_ln_kernel(const ushort* __restrict__ xres, float* __restrict__ f,
                   const float* __restrict__ g, const float* __restrict__ bb) {
    const int wv   = threadIdx.x >> 6;
    const int lane = threadIdx.x & 63;
    const int wid  = blockIdx.x * 4 + wv;
    const size_t ob = (size_t)wid * Dd;

    ushort4 a0 = *(const ushort4*)(xres + ob + lane * 4);
    float4  f0 = *(const float4*)(f    + ob + lane * 4);
    ushort4 a1 = *(const ushort4*)(xres + ob + 256 + lane * 4);
    float4  f1 = *(const float4*)(f    + ob + 256 + lane * 4);
    float r2[8];
    r2[0] = bf2f(a0.x) + f0.x; r2[1] = bf2f(a0.y) + f0.y;
    r2[2] = bf2f(a0.z) + f0.z; r2[3] = bf2f(a0.w) + f0.w;
    r2[4] = bf2f(a1.x) + f1.x; r2[5] = bf2f(a1.y) + f1.y;
    r2[6] = bf2f(a1.z) + f1.z; r2[7] = bf2f(a1.w) + f1.w;

    float sm = 0.f, sq = 0.f;
    #pragma unroll
    for (int j = 0; j < 8; ++j) { sm += r2[j]; sq = fmaf(r2[j], r2[j], sq); }
    #pragma unroll
    for (int m = 1; m < 64; m <<= 1) {
        sm += __shfl_xor(sm, m, 64);
        sq += __shfl_xor(sq, m, 64);
    }
    const float mu   = sm * (1.f / Dd);
    const float var  = sq * (1.f / Dd) - mu * mu;
    const float rstd = rsqrtf(var + EPSf);

    float4 g0 = *(const float4*)(g  + lane * 4);
    float4 b0 = *(const float4*)(bb + lane * 4);
    float4 g1 = *(const float4*)(g  + 256 + lane * 4);
    float4 b1 = *(const float4*)(bb + 256 + lane * 4);
    float4 o0, o1;
    o0.x = (r2[0] - mu) * rstd * g0.x + b0.x;
    o0.y = (r2[1] - mu) * rstd * g0.y + b0.y;
    o0.z = (r2[2] - mu) * rstd * g0.z + b0.z;
    o0.w = (r2[3] - mu) * rstd * g0.w + b0.w;
    o1.x = (r2[4] - mu) * rstd * g1.x + b1.x;
    o1.y = (r2[5] - mu) * rstd * g1.y + b1.y;
    o1.z = (r2[6] - mu) * rstd * g1.z + b1.z;
    o1.w = (r2[7] - mu) * rstd * g1.w + b1.w;
    *(float4*)(f + ob + lane * 4)       = o0;
    *(float4*)(f + ob + 256 + lane * 4) = o1;
}

// ---------------------------------------------------------------------------
// bf16 MFMA NT GEMM (m97 structure, ~873 TF; XCD swizzle validated r10)
// ---------------------------------------------------------------------------
template<int RELU, int BF16OUT>
__global__ __launch_bounds__(256)
void gemm_bf16(const ushort* __restrict__ A, const ushort* __restrict__ B,
               const float* __restrict__ bias, void* __restrict__ Cout,
               int M, int N, int K) {
    __shared__ ushort As[128 * 32];          // [row][k] bf16, 8KB
    __shared__ ushort Bs[128 * 32];
    const int tid  = threadIdx.x;
    const int wid  = tid >> 6;
    const int lane = tid & 63;
    const int wr   = wid >> 1;               // wave quadrant row (0/1)
    const int wc   = wid & 1;                // wave quadrant col (0/1)

    // ---- XCD-aware bijective swizzle (m204) ----
    const int nwg  = (int)(gridDim.x * gridDim.y);
    const int orig = (int)(blockIdx.y * gridDim.x + blockIdx.x);
    const int q    = nwg >> 3, r = nwg & 7;
    const int xcd  = orig & 7, seq = orig >> 3;
    const int swz  = (xcd < r ? xcd * (q + 1) : r * (q + 1) + (xcd - r) * q) + seq;
    const int bxT  = swz % (int)gridDim.x;   // N-tile (fast dim)
    const int byT  = swz / (int)gridDim.x;   // M-tile
    const size_t bm = (size_t)byT * 128;
    const size_t bn = (size_t)bxT * 128;

    const ushort* gA0 = A + (bm + wid * 32 + (lane >> 2)) * (size_t)K + (lane & 3) * 8;
    const ushort* gA1 = gA0 + (size_t)16 * K;
    const ushort* gB0 = B + (bn + wid * 32 + (lane >> 2)) * (size_t)K + (lane & 3) * 8;
    const ushort* gB1 = gB0 + (size_t)16 * K;
    ushort* lA0 = &As[wid * 1024];
    ushort* lA1 = lA0 + 512;
    ushort* lB0 = &Bs[wid * 1024];
    ushort* lB1 = lB0 + 512;

    const ushort* aPtr = &As[(wr * 64 + (lane & 15)) * 32 + (lane >> 4) * 8];
    const ushort* bPtr = &Bs[(wc * 64 + (lane & 15)) * 32 + (lane >> 4) * 8];

    f32x4 acc[4][4];
    #pragma unroll
    for (int i = 0; i < 4; ++i)
        #pragma unroll
        for (int j = 0; j < 4; ++j) acc[i][j] = (f32x4){0.f, 0.f, 0.f, 0.f};

    #define GLDS(gp, lp) __builtin_amdgcn_global_load_lds( \
        (const __attribute__((address_space(1))) void*)(gp), \
        (__attribute__((address_space(3))) void*)(lp), 16, 0, 0)

    for (int k0 = 0; k0 < K; k0 += 32) {
        GLDS(gA0 + k0, lA0);
        GLDS(gA1 + k0, lA1);
        GLDS(gB0 + k0, lB0);
        GLDS(gB1 + k0, lB1);
        __syncthreads();
        short8 af[4], bf_[4];
        #pragma unroll
        for (int mt = 0; mt < 4; ++mt) af[mt]  = *(const short8*)(aPtr + mt * 512);
        #pragma unroll
        for (int nt = 0; nt < 4; ++nt) bf_[nt] = *(const short8*)(bPtr + nt * 512);
        #pragma unroll
        for (int mt = 0; mt < 4; ++mt)
            #pragma unroll
            for (int nt = 0; nt < 4; ++nt)
                acc[mt][nt] = __builtin_amdgcn_mfma_f32_16x16x32_bf16(
                    af[mt], bf_[nt], acc[mt][nt], 0, 0, 0);
        __syncthreads();
    }
    #undef GLDS

    float* Cf  = (float*)Cout;
    ushort* Cb = (ushort*)Cout;
    #pragma unroll
    for (int nt = 0; nt < 4; ++nt) {
        const int cn = (int)bn + wc * 64 + nt * 16 + (lane & 15);
        const float bv = bias[cn];
        #pragma unroll
        for (int mt = 0; mt < 4; ++mt) {
            const size_t rowb = bm + wr * 64 + mt * 16 + (lane >> 4) * 4;
            #pragma unroll
            for (int rr = 0; rr < 4; ++rr) {
                float v = acc[mt][nt][rr] + bv;
                if (RELU) v = fmaxf(v, 0.f);
                if (BF16OUT) Cb[(rowb + rr) * (size_t)N + cn] = f2bf(v);
                else         Cf[(rowb + rr) * (size_t)N + cn] = v;
            }
        }
    }
}

// ---------------------------------------------------------------------------
// Decoder: out[b] = x[b, S-1, :] . dec_w + dec_b
// ---------------------------------------------------------------------------
__global__ __launch_bounds__(64)
void decode_kernel(const float* __restrict__ x, const float* __restrict__ dw,
                   const float* __restrict__ db, float* __restrict__ out) {
    const int b = blockIdx.x;
    const int lane = threadIdx.x;
    const float* r = x + ((size_t)b * Ss + (Ss - 1)) * Dd;
    float acc = 0.f;
    #pragma unroll
    for (int j = 0; j < 8; ++j) acc = fmaf(r[j*64 + lane], dw[j*64 + lane], acc);
    #pragma unroll
    for (int m = 1; m < 64; m <<= 1) acc += __shfl_xor(acc, m, 64);
    if (lane == 0) out[b] = acc + db[0];
}

// ---------------------------------------------------------------------------
extern "C" void kernel_launch(void* const* d_in, const int* in_sizes, int n_in,
                              void* d_out, int out_size, void* d_ws, size_t ws_size,
                              hipStream_t stream) {
    const float* src   = (const float*)d_in[0];
    const float* pe    = (const float*)d_in[1];
    const float* enc_w = (const float*)d_in[2];
    const float* enc_b = (const float*)d_in[3];
    const float* l1_w  = (const float*)d_in[4];
    const float* l1_b  = (const float*)d_in[5];
    const float* l2_w  = (const float*)d_in[6];
    const float* l2_b  = (const float*)d_in[7];
    const float* n1_g  = (const float*)d_in[8];
    const float* n1_b  = (const float*)d_in[9];
    const float* n2_g  = (const float*)d_in[10];
    const float* n2_b  = (const float*)d_in[11];
    const float* dec_w = (const float*)d_in[12];
    const float* dec_b = (const float*)d_in[13];
    float* out = (float*)d_out;

    // WORKSPACE (r12 post-mortem: ws_size ~ 256MB inferred from r10 WRITE_SIZE
    // matching chunkM=18432; r12's 248MB fixed collapsed chunkM to 2048 ->
    // 192 tiny GEMMs -> 6ms). New fixed = 152MB:
    //   fbuf fp32 64MB | xbf_a bf16 32MB | xbf_b bf16 32MB | w1bf 12 | w2bf 12
    //   hbf = remainder (~104MB at ws=256 -> chunkM 26624 -> 2 chunks/layer).
    // Attention stream is bf16-only now (it was already bf16-quantized for
    // GEMM1; the fp32 copy was redundant). Chunk floor raised to 2048.
    const size_t NTOK = (size_t)BS * Dd;          // 16.78M
    float*  fbuf  = (float*)d_ws;                 // encode out / FFN out / final
    ushort* xbfA  = (ushort*)(fbuf + NTOK);
    ushort* xbfB  = xbfA + NTOK;
    ushort* w1bf  = xbfB + NTOK;
    ushort* w2bf  = w1bf + (size_t)Ll * FFf * Dd;
    ushort* hbf   = w2bf + (size_t)Ll * FFf * Dd;

    const size_t fixedBytes = (size_t)((char*)hbf - (char*)d_ws);   // 152MB
    size_t hBytes = ws_size > fixedBytes ? ws_size - fixedBytes : 0;
    int    chunkM = (int)(hBytes / ((size_t)FFf * sizeof(ushort)));
    if (chunkM > BS) chunkM = BS;
    chunkM &= ~127;                      // multiple of the GEMM tile height
    if (chunkM < 2048) chunkM = 2048;    // floor: bounds dispatch explosion

    const int wn4 = Ll * FFf * Dd / 4;
    convert_bf16<<<1024, 256, 0, stream>>>(l1_w, w1bf, wn4);
    convert_bf16<<<1024, 256, 0, stream>>>(l2_w, w2bf, wn4);

    encode_kernel<<<2048, 256, 0, stream>>>(src, pe, enc_w, enc_b, fbuf);

    attn_ln_kernel<<<BS / 4, 256, 0, stream>>>(fbuf, xbfA, n1_g, n1_b);

    ushort* xbfCur = xbfA;
    ushort* xbfNxt = xbfB;
    for (int i = 0; i < Ll; ++i) {
        for (int m0 = 0; m0 < BS; m0 += chunkM) {
            int mh = (BS - m0) < chunkM ? (BS - m0) : chunkM;
            gemm_bf16<1, 1><<<dim3(FFf / 128, mh / 128), 256, 0, stream>>>(
                xbfCur + (size_t)m0 * Dd, w1bf + (size_t)i * FFf * Dd,
                l1_b + i * FFf, hbf, mh, FFf, Dd);
            gemm_bf16<0, 0><<<dim3(Dd / 128, mh / 128), 256, 0, stream>>>(
                hbf, w2bf + (size_t)i * Dd * FFf, l2_b + i * Dd,
                fbuf + (size_t)m0 * Dd, mh, Dd, FFf);
        }
        if (i < Ll - 1) {
            fused_tail_attn_kernel<<<BS / 4, 256, 0, stream>>>(
                xbfCur, fbuf,
                n2_g + i * Dd, n2_b + i * Dd,             // LN2 (layer i)
                n1_g + (i + 1) * Dd, n1_b + (i + 1) * Dd, // LN1 (layer i+1)
                xbfNxt);
            ushort* t = xbfCur; xbfCur = xbfNxt; xbfNxt = t;
        } else {
            add_ln_kernel<<<BS / 4, 256, 0, stream>>>(
                xbfCur, fbuf, n2_g + i * Dd, n2_b + i * Dd);
        }
    }

    decode_kernel<<<Bb, 64, 0, stream>>>(fbuf, dec_w, dec_b, out);
}

// Round 15
// 1607.816 us; speedup vs baseline: 3.7853x; 1.3102x over previous
//
#include <hip/hip_runtime.h>
#include <hip/hip_bf16.h>
#include <math.h>

// Problem constants
constexpr int Bb  = 16;
constexpr int Ss  = 2048;
constexpr int INd = 32;
constexpr int Dd  = 512;
constexpr int FFf = 2048;
constexpr int Ll  = 6;
constexpr int BS  = Bb * Ss;          // 32768 tokens
constexpr float EPSf = 1e-5f;

typedef __attribute__((ext_vector_type(8))) short short8;   // 8 bf16 (4 VGPRs)
typedef __attribute__((ext_vector_type(4))) float f32x4;

__device__ __forceinline__ ushort f2bf(float f) {
    uint u = __float_as_uint(f);
    uint r = (u + 0x7fffu + ((u >> 16) & 1u)) >> 16;        // round-nearest-even
    return (ushort)r;
}
__device__ __forceinline__ float bf2f(ushort u) {
    return __uint_as_float((uint)u << 16);
}

// ---------------------------------------------------------------------------
// fp32 -> bf16 bulk convert (weights, once per launch)
// ---------------------------------------------------------------------------
__global__ __launch_bounds__(256)
void convert_bf16(const float* __restrict__ in, ushort* __restrict__ out, int n4) {
    int i = blockIdx.x * blockDim.x + threadIdx.x;
    int stride = gridDim.x * blockDim.x;
    for (; i < n4; i += stride) {
        float4 v = ((const float4*)in)[i];
        ushort4 o;
        o.x = f2bf(v.x); o.y = f2bf(v.y); o.z = f2bf(v.z); o.w = f2bf(v.w);
        ((ushort4*)out)[i] = o;
    }
}

// ---------------------------------------------------------------------------
// Encoder v2: register-resident enc_w (validated r10)
// NOTE: reproduces the reference's pe[:x.shape[0]] broadcast (per-BATCH pe row)
// ---------------------------------------------------------------------------
__global__ __launch_bounds__(256)
void encode_kernel(const float* __restrict__ src, const float* __restrict__ pe,
                   const float* __restrict__ ew, const float* __restrict__ eb,
                   float* __restrict__ y) {
    __shared__ float s_src[8][32];
    const int tid = threadIdx.x;
    const int d0  = 2 * tid;                 // dims d0, d0+1
    float w0[32], w1[32];
    #pragma unroll
    for (int k = 0; k < 32; k += 4) {
        float4 a = *(const float4*)(ew + (size_t)d0 * INd + k);
        float4 b = *(const float4*)(ew + (size_t)(d0 + 1) * INd + k);
        w0[k] = a.x; w0[k+1] = a.y; w0[k+2] = a.z; w0[k+3] = a.w;
        w1[k] = b.x; w1[k+1] = b.y; w1[k+2] = b.z; w1[k+3] = b.w;
    }
    const float e0 = eb[d0], e1 = eb[d0 + 1];
    const float sqrtD = 22.62741699796952f;

    for (int t0 = 0; t0 < BS / 2048; t0 += 8) {
        __syncthreads();                     // protect s_src reuse
        {
            const int j = tid >> 5, e = tid & 31;
            const int tok = (int)blockIdx.x + (t0 + j) * 2048;
            s_src[j][e] = src[(size_t)tok * INd + e];
        }
        __syncthreads();
        #pragma unroll
        for (int j = 0; j < 8; ++j) {
            const int tok = (int)blockIdx.x + (t0 + j) * 2048;
            const int b   = tok >> 11;       // batch index
            float a0 = 0.f, a1 = 0.f;
            #pragma unroll
            for (int k = 0; k < 32; ++k) {
                const float sv = s_src[j][k];
                a0 = fmaf(sv, w0[k], a0);
                a1 = fmaf(sv, w1[k], a1);
            }
            const float2 pv = *(const float2*)(pe + (size_t)b * Dd + d0);
            float2 o;
            o.x = (a0 + e0) * sqrtD + pv.x;
            o.y = (a1 + e1) * sqrtD + pv.y;
            *(float2*)(y + (size_t)tok * Dd + d0) = o;
        }
    }
}

// ---------------------------------------------------------------------------
// XCD-aware token-block swizzle (m204 bijective; nb=8192 divisible by 8)
// ---------------------------------------------------------------------------
__device__ __forceinline__ int swz_block(int ob, int nb) {
    return (ob & 7) * (nb >> 3) + (ob >> 3);
}

// ---------------------------------------------------------------------------
// Layer-0 attention + LN1: reads fp32 encode output, writes bf16 stream.
// ---------------------------------------------------------------------------
__global__ __launch_bounds__(256)
void attn_ln_kernel(const float* __restrict__ x, ushort* __restrict__ ybf,
                    const float* __restrict__ g, const float* __restrict__ bb) {
    const int wv   = threadIdx.x >> 6;
    const int lane = threadIdx.x & 63;
    const int wid  = swz_block((int)blockIdx.x, (int)gridDim.x) * 4 + wv;
    const int b    = wid >> 11;
    const int s    = wid & (Ss - 1);
    const float* base = x + (size_t)b * Ss * Dd;

    float rows[7][8];
    #pragma unroll
    for (int o = 0; o < 7; ++o) {
        int sp = s + o - 3;
        int sc = sp < 0 ? 0 : (sp > Ss - 1 ? Ss - 1 : sp);
        const float* r = base + (size_t)sc * Dd;
        float4 v0 = *(const float4*)(r + lane * 4);
        float4 v1 = *(const float4*)(r + 256 + lane * 4);
        rows[o][0] = v0.x; rows[o][1] = v0.y; rows[o][2] = v0.z; rows[o][3] = v0.w;
        rows[o][4] = v1.x; rows[o][5] = v1.y; rows[o][6] = v1.z; rows[o][7] = v1.w;
    }

    const float scale = 0.04419417382415922f;   // 1/sqrt(512)
    float score[7];
    #pragma unroll
    for (int o = 0; o < 7; ++o) {
        float p = 0.f;
        #pragma unroll
        for (int j = 0; j < 8; ++j) p = fmaf(rows[3][j], rows[o][j], p);
        #pragma unroll
        for (int m = 1; m < 64; m <<= 1) p += __shfl_xor(p, m, 64);
        int sp = s + o - 3;
        score[o] = (sp >= 0 && sp < Ss) ? p * scale : -1e9f;
    }
    float mx = score[0];
    #pragma unroll
    for (int o = 1; o < 7; ++o) mx = fmaxf(mx, score[o]);
    float w[7], wsum = 0.f;
    #pragma unroll
    for (int o = 0; o < 7; ++o) { w[o] = __expf(score[o] - mx); wsum += w[o]; }
    const float inv = 1.f / wsum;
    #pragma unroll
    for (int o = 0; o < 7; ++o) w[o] *= inv;

    float r2[8];
    #pragma unroll
    for (int j = 0; j < 8; ++j) {
        float acc = rows[3][j];                 // residual (pre-LN x)
        #pragma unroll
        for (int o = 0; o < 7; ++o) acc = fmaf(w[o], rows[o][j], acc);
        r2[j] = acc;
    }

    float sm = 0.f, sq = 0.f;
    #pragma unroll
    for (int j = 0; j < 8; ++j) { sm += r2[j]; sq = fmaf(r2[j], r2[j], sq); }
    #pragma unroll
    for (int m = 1; m < 64; m <<= 1) {
        sm += __shfl_xor(sm, m, 64);
        sq += __shfl_xor(sq, m, 64);
    }
    const float mu   = sm * (1.f / Dd);
    const float var  = sq * (1.f / Dd) - mu * mu;
    const float rstd = rsqrtf(var + EPSf);

    const size_t ob = (size_t)wid * Dd;
    float4 g0 = *(const float4*)(g  + lane * 4);
    float4 b0 = *(const float4*)(bb + lane * 4);
    float4 g1 = *(const float4*)(g  + 256 + lane * 4);
    float4 b1 = *(const float4*)(bb + 256 + lane * 4);
    ushort4 q0, q1;
    q0.x = f2bf((r2[0] - mu) * rstd * g0.x + b0.x);
    q0.y = f2bf((r2[1] - mu) * rstd * g0.y + b0.y);
    q0.z = f2bf((r2[2] - mu) * rstd * g0.z + b0.z);
    q0.w = f2bf((r2[3] - mu) * rstd * g0.w + b0.w);
    q1.x = f2bf((r2[4] - mu) * rstd * g1.x + b1.x);
    q1.y = f2bf((r2[5] - mu) * rstd * g1.y + b1.y);
    q1.z = f2bf((r2[6] - mu) * rstd * g1.z + b1.z);
    q1.w = f2bf((r2[7] - mu) * rstd * g1.w + b1.w);
    *(ushort4*)(ybf + ob + lane * 4)       = q0;
    *(ushort4*)(ybf + ob + 256 + lane * 4) = q1;
}

// ---------------------------------------------------------------------------
// FUSED layer tail + next attention (layers 0..4) — validated r13 (left top-5)
// ---------------------------------------------------------------------------
__global__ __launch_bounds__(256)
void fused_tail_attn_kernel(const ushort* __restrict__ xb, const float* __restrict__ ff,
                            const float* __restrict__ g2, const float* __restrict__ b2,
                            const float* __restrict__ g1, const float* __restrict__ b1,
                            ushort* __restrict__ ybf) {
    const int wv   = threadIdx.x >> 6;
    const int lane = threadIdx.x & 63;
    const int wid  = swz_block((int)blockIdx.x, (int)gridDim.x) * 4 + wv;
    const int b    = wid >> 11;
    const int s    = wid & (Ss - 1);
    const size_t roff = (size_t)b * Ss * Dd;

    float4 G2a = *(const float4*)(g2 + lane * 4);
    float4 G2b = *(const float4*)(g2 + 256 + lane * 4);
    float4 B2a = *(const float4*)(b2 + lane * 4);
    float4 B2b = *(const float4*)(b2 + 256 + lane * 4);

    float rows[7][8];
    #pragma unroll
    for (int o = 0; o < 7; ++o) {
        int sp = s + o - 3;
        int sc = sp < 0 ? 0 : (sp > Ss - 1 ? Ss - 1 : sp);
        const ushort* xr = xb + roff + (size_t)sc * Dd;
        const float*  fr = ff + roff + (size_t)sc * Dd;
        ushort4 x0 = *(const ushort4*)(xr + lane * 4);
        float4  f0 = *(const float4*)(fr + lane * 4);
        ushort4 x1 = *(const ushort4*)(xr + 256 + lane * 4);
        float4  f1 = *(const float4*)(fr + 256 + lane * 4);
        float r2[8];
        r2[0] = bf2f(x0.x) + f0.x; r2[1] = bf2f(x0.y) + f0.y;
        r2[2] = bf2f(x0.z) + f0.z; r2[3] = bf2f(x0.w) + f0.w;
        r2[4] = bf2f(x1.x) + f1.x; r2[5] = bf2f(x1.y) + f1.y;
        r2[6] = bf2f(x1.z) + f1.z; r2[7] = bf2f(x1.w) + f1.w;

        float sm = 0.f, sq = 0.f;
        #pragma unroll
        for (int j = 0; j < 8; ++j) { sm += r2[j]; sq = fmaf(r2[j], r2[j], sq); }
        #pragma unroll
        for (int m = 1; m < 64; m <<= 1) {
            sm += __shfl_xor(sm, m, 64);
            sq += __shfl_xor(sq, m, 64);
        }
        const float mu   = sm * (1.f / Dd);
        const float var  = sq * (1.f / Dd) - mu * mu;
        const float rstd = rsqrtf(var + EPSf);
        rows[o][0] = (r2[0] - mu) * rstd * G2a.x + B2a.x;
        rows[o][1] = (r2[1] - mu) * rstd * G2a.y + B2a.y;
        rows[o][2] = (r2[2] - mu) * rstd * G2a.z + B2a.z;
        rows[o][3] = (r2[3] - mu) * rstd * G2a.w + B2a.w;
        rows[o][4] = (r2[4] - mu) * rstd * G2b.x + B2b.x;
        rows[o][5] = (r2[5] - mu) * rstd * G2b.y + B2b.y;
        rows[o][6] = (r2[6] - mu) * rstd * G2b.z + B2b.z;
        rows[o][7] = (r2[7] - mu) * rstd * G2b.w + B2b.w;
    }

    const float scale = 0.04419417382415922f;   // 1/sqrt(512)
    float score[7];
    #pragma unroll
    for (int o = 0; o < 7; ++o) {
        float p = 0.f;
        #pragma unroll
        for (int j = 0; j < 8; ++j) p = fmaf(rows[3][j], rows[o][j], p);
        #pragma unroll
        for (int m = 1; m < 64; m <<= 1) p += __shfl_xor(p, m, 64);
        int sp = s + o - 3;
        score[o] = (sp >= 0 && sp < Ss) ? p * scale : -1e9f;
    }
    float mx = score[0];
    #pragma unroll
    for (int o = 1; o < 7; ++o) mx = fmaxf(mx, score[o]);
    float w[7], wsum = 0.f;
    #pragma unroll
    for (int o = 0; o < 7; ++o) { w[o] = __expf(score[o] - mx); wsum += w[o]; }
    const float inv = 1.f / wsum;
    #pragma unroll
    for (int o = 0; o < 7; ++o) w[o] *= inv;

    float r2[8];
    #pragma unroll
    for (int j = 0; j < 8; ++j) {
        float acc = rows[3][j];                 // residual (LN2'd center row)
        #pragma unroll
        for (int o = 0; o < 7; ++o) acc = fmaf(w[o], rows[o][j], acc);
        r2[j] = acc;
    }

    float sm = 0.f, sq = 0.f;
    #pragma unroll
    for (int j = 0; j < 8; ++j) { sm += r2[j]; sq = fmaf(r2[j], r2[j], sq); }
    #pragma unroll
    for (int m = 1; m < 64; m <<= 1) {
        sm += __shfl_xor(sm, m, 64);
        sq += __shfl_xor(sq, m, 64);
    }
    const float mu   = sm * (1.f / Dd);
    const float var  = sq * (1.f / Dd) - mu * mu;
    const float rstd = rsqrtf(var + EPSf);

    const size_t ob = (size_t)wid * Dd;
    float4 g0 = *(const float4*)(g1 + lane * 4);
    float4 b0 = *(const float4*)(b1 + lane * 4);
    float4 g1v = *(const float4*)(g1 + 256 + lane * 4);
    float4 b1v = *(const float4*)(b1 + 256 + lane * 4);
    ushort4 q0, q1;
    q0.x = f2bf((r2[0] - mu) * rstd * g0.x + b0.x);
    q0.y = f2bf((r2[1] - mu) * rstd * g0.y + b0.y);
    q0.z = f2bf((r2[2] - mu) * rstd * g0.z + b0.z);
    q0.w = f2bf((r2[3] - mu) * rstd * g0.w + b0.w);
    q1.x = f2bf((r2[4] - mu) * rstd * g1v.x + b1v.x);
    q1.y = f2bf((r2[5] - mu) * rstd * g1v.y + b1v.y);
    q1.z = f2bf((r2[6] - mu) * rstd * g1v.z + b1v.z);
    q1.w = f2bf((r2[7] - mu) * rstd * g1v.w + b1v.w);
    *(ushort4*)(ybf + ob + lane * 4)       = q0;
    *(ushort4*)(ybf + ob + 256 + lane * 4) = q1;
}

// ---------------------------------------------------------------------------
// Final-layer residual add + LN2 (in-place on fp32 f; decode reads it)
// ---------------------------------------------------------------------------
__global__ __launch_bounds__(256)
void add_ln_kernel(const ushort* __restrict__ xres, float* __restrict__ f,
                   const float* __restrict__ g, const float* __restrict__ bb) {
    const int wv   = threadIdx.x >> 6;
    const int lane = threadIdx.x & 63;
    const int wid  = blockIdx.x * 4 + wv;
    const size_t ob = (size_t)wid * Dd;

    ushort4 a0 = *(const ushort4*)(xres + ob + lane * 4);
    float4  f0 = *(const float4*)(f    + ob + lane * 4);
    ushort4 a1 = *(const ushort4*)(xres + ob + 256 + lane * 4);
    float4  f1 = *(const float4*)(f    + ob + 256 + lane * 4);
    float r2[8];
    r2[0] = bf2f(a0.x) + f0.x; r2[1] = bf2f(a0.y) + f0.y;
    r2[2] = bf2f(a0.z) + f0.z; r2[3] = bf2f(a0.w) + f0.w;
    r2[4] = bf2f(a1.x) + f1.x; r2[5] = bf2f(a1.y) + f1.y;
    r2[6] = bf2f(a1.z) + f1.z; r2[7] = bf2f(a1.w) + f1.w;

    float sm = 0.f, sq = 0.f;
    #pragma unroll
    for (int j = 0; j < 8; ++j) { sm += r2[j]; sq = fmaf(r2[j], r2[j], sq); }
    #pragma unroll
    for (int m = 1; m < 64; m <<= 1) {
        sm += __shfl_xor(sm, m, 64);
        sq += __shfl_xor(sq, m, 64);
    }
    const float mu   = sm * (1.f / Dd);
    const float var  = sq * (1.f / Dd) - mu * mu;
    const float rstd = rsqrtf(var + EPSf);

    float4 g0 = *(const float4*)(g  + lane * 4);
    float4 b0 = *(const float4*)(bb + lane * 4);
    float4 g1 = *(const float4*)(g  + 256 + lane * 4);
    float4 b1 = *(const float4*)(bb + 256 + lane * 4);
    float4 o0, o1;
    o0.x = (r2[0] - mu) * rstd * g0.x + b0.x;
    o0.y = (r2[1] - mu) * rstd * g0.y + b0.y;
    o0.z = (r2[2] - mu) * rstd * g0.z + b0.z;
    o0.w = (r2[3] - mu) * rstd * g0.w + b0.w;
    o1.x = (r2[4] - mu) * rstd * g1.x + b1.x;
    o1.y = (r2[5] - mu) * rstd * g1.y + b1.y;
    o1.z = (r2[6] - mu) * rstd * g1.z + b1.z;
    o1.w = (r2[7] - mu) * rstd * g1.w + b1.w;
    *(float4*)(f + ob + lane * 4)       = o0;
    *(float4*)(f + ob + 256 + lane * 4) = o1;
}

// ---------------------------------------------------------------------------
// bf16 MFMA NT GEMM v2: 128x128 tile, BK=64 (2 barriers per 64-K: halves
// fixed per-iter costs vs BK=32 — r13 PMC: 478 TF, MfmaUtil 20%, per-iter
// barrier/drain-bound). LDS 32KB -> still 5 blocks/CU. ds_read bank conflict
// (16-way at 128B row stride) fixed T2-style: LDS linear (global_load_lds
// requirement, m104), global source k pre-swizzled by XOR involution
// k_hw ^= (row&7)*8, reads apply the same XOR -> uniform bank distribution.
// Accumulation order per acc element unchanged (k-ascending) -> bit-identical.
// ---------------------------------------------------------------------------
template<int RELU, int BF16OUT>
__global__ __launch_bounds__(256)
void gemm_bf16(const ushort* __restrict__ A, const ushort* __restrict__ B,
               const float* __restrict__ bias, void* __restrict__ Cout,
               int M, int N, int K) {
    __shared__ ushort As[128 * 64];          // [row][k] bf16 swizzled, 16KB
    __shared__ ushort Bs[128 * 64];
    const int tid  = threadIdx.x;
    const int wid  = tid >> 6;
    const int lane = tid & 63;
    const int wr   = wid >> 1;               // wave quadrant row (0/1)
    const int wc   = wid & 1;                // wave quadrant col (0/1)

    // ---- XCD-aware bijective swizzle (m204) ----
    const int nwg  = (int)(gridDim.x * gridDim.y);
    const int orig = (int)(blockIdx.y * gridDim.x + blockIdx.x);
    const int q    = nwg >> 3, r = nwg & 7;
    const int xcd  = orig & 7, seq = orig >> 3;
    const int swz  = (xcd < r ? xcd * (q + 1) : r * (q + 1) + (xcd - r) * q) + seq;
    const int bxT  = swz % (int)gridDim.x;   // N-tile (fast dim)
    const int byT  = swz / (int)gridDim.x;   // M-tile
    const size_t bm = (size_t)byT * 128;
    const size_t bn = (size_t)bxT * 128;

    // staging: wave stages rows [wid*32, wid*32+32), 4 GLDS per side per iter;
    // GLDS i covers rows i*8+(lane>>3), 16B at swizzled k: the 8 lanes of a
    // row-group read a permutation of the row's 128B line (still coalesced).
    const int swzk = 8 * ((lane & 7) ^ (lane >> 3));       // halfword offset
    const ushort* gA0 = A + (bm + wid * 32 + (lane >> 3)) * (size_t)K + swzk;
    const ushort* gB0 = B + (bn + wid * 32 + (lane >> 3)) * (size_t)K + swzk;
    ushort* lA0 = &As[wid * 32 * 64];        // wave-uniform dest bases
    ushort* lB0 = &Bs[wid * 32 * 64];

    // fragment reads: row = quad*64 + mt*16 + (lane&15); logical k_hw =
    // (lane>>4)*8 + kk*32; physical = logical ^ ((lane&7)*8)  [row&7==lane&7]
    const int koff0 = ((lane >> 4) * 8) ^ ((lane & 7) * 8);
    const int koff1 = (((lane >> 4) * 8) + 32) ^ ((lane & 7) * 8);
    const ushort* aPtr = &As[(wr * 64 + (lane & 15)) * 64];
    const ushort* bPtr = &Bs[(wc * 64 + (lane & 15)) * 64];

    f32x4 acc[4][4];
    #pragma unroll
    for (int i = 0; i < 4; ++i)
        #pragma unroll
        for (int j = 0; j < 4; ++j) acc[i][j] = (f32x4){0.f, 0.f, 0.f, 0.f};

    #define GLDS(gp, lp) __builtin_amdgcn_global_load_lds( \
        (const __attribute__((address_space(1))) void*)(gp), \
        (__attribute__((address_space(3))) void*)(lp), 16, 0, 0)

    for (int k0 = 0; k0 < K; k0 += 64) {
        #pragma unroll
        for (int i = 0; i < 4; ++i) {
            GLDS(gA0 + (size_t)(i * 8) * K + k0, lA0 + i * 512);
            GLDS(gB0 + (size_t)(i * 8) * K + k0, lB0 + i * 512);
        }
        __syncthreads();
        #pragma unroll
        for (int kk = 0; kk < 2; ++kk) {
            const int ko = kk ? koff1 : koff0;
            short8 af[4], bf_[4];
            #pragma unroll
            for (int mt = 0; mt < 4; ++mt) af[mt]  = *(const short8*)(aPtr + mt * 1024 + ko);
            #pragma unroll
            for (int nt = 0; nt < 4; ++nt) bf_[nt] = *(const short8*)(bPtr + nt * 1024 + ko);
            #pragma unroll
            for (int mt = 0; mt < 4; ++mt)
                #pragma unroll
                for (int nt = 0; nt < 4; ++nt)
                    acc[mt][nt] = __builtin_amdgcn_mfma_f32_16x16x32_bf16(
                        af[mt], bf_[nt], acc[mt][nt], 0, 0, 0);
        }
        __syncthreads();
    }
    #undef GLDS

    float* Cf  = (float*)Cout;
    ushort* Cb = (ushort*)Cout;
    #pragma unroll
    for (int nt = 0; nt < 4; ++nt) {
        const int cn = (int)bn + wc * 64 + nt * 16 + (lane & 15);
        const float bv = bias[cn];
        #pragma unroll
        for (int mt = 0; mt < 4; ++mt) {
            const size_t rowb = bm + wr * 64 + mt * 16 + (lane >> 4) * 4;
            #pragma unroll
            for (int rr = 0; rr < 4; ++rr) {
                float v = acc[mt][nt][rr] + bv;
                if (RELU) v = fmaxf(v, 0.f);
                if (BF16OUT) Cb[(rowb + rr) * (size_t)N + cn] = f2bf(v);
                else         Cf[(rowb + rr) * (size_t)N + cn] = v;
            }
        }
    }
}

// ---------------------------------------------------------------------------
// Decoder: out[b] = x[b, S-1, :] . dec_w + dec_b
// ---------------------------------------------------------------------------
__global__ __launch_bounds__(64)
void decode_kernel(const float* __restrict__ x, const float* __restrict__ dw,
                   const float* __restrict__ db, float* __restrict__ out) {
    const int b = blockIdx.x;
    const int lane = threadIdx.x;
    const float* r = x + ((size_t)b * Ss + (Ss - 1)) * Dd;
    float acc = 0.f;
    #pragma unroll
    for (int j = 0; j < 8; ++j) acc = fmaf(r[j*64 + lane], dw[j*64 + lane], acc);
    #pragma unroll
    for (int m = 1; m < 64; m <<= 1) acc += __shfl_xor(acc, m, 64);
    if (lane == 0) out[b] = acc + db[0];
}

// ---------------------------------------------------------------------------
extern "C" void kernel_launch(void* const* d_in, const int* in_sizes, int n_in,
                              void* d_out, int out_size, void* d_ws, size_t ws_size,
                              hipStream_t stream) {
    const float* src   = (const float*)d_in[0];
    const float* pe    = (const float*)d_in[1];
    const float* enc_w = (const float*)d_in[2];
    const float* enc_b = (const float*)d_in[3];
    const float* l1_w  = (const float*)d_in[4];
    const float* l1_b  = (const float*)d_in[5];
    const float* l2_w  = (const float*)d_in[6];
    const float* l2_b  = (const float*)d_in[7];
    const float* n1_g  = (const float*)d_in[8];
    const float* n1_b  = (const float*)d_in[9];
    const float* n2_g  = (const float*)d_in[10];
    const float* n2_b  = (const float*)d_in[11];
    const float* dec_w = (const float*)d_in[12];
    const float* dec_b = (const float*)d_in[13];
    float* out = (float*)d_out;

    // WORKSPACE (ws ~256MB confirmed r13): fixed 152MB =
    //   fbuf fp32 64MB | xbf_a 32MB | xbf_b 32MB | w1bf 12MB | w2bf 12MB
    //   hbf = remainder. Chunks BALANCED: ceil-split BS into equal
    //   128-multiples (r13 ran 26624+6144; now 16384+16384).
    const size_t NTOK = (size_t)BS * Dd;          // 16.78M
    float*  fbuf  = (float*)d_ws;                 // encode out / FFN out / final
    ushort* xbfA  = (ushort*)(fbuf + NTOK);
    ushort* xbfB  = xbfA + NTOK;
    ushort* w1bf  = xbfB + NTOK;
    ushort* w2bf  = w1bf + (size_t)Ll * FFf * Dd;
    ushort* hbf   = w2bf + (size_t)Ll * FFf * Dd;

    const size_t fixedBytes = (size_t)((char*)hbf - (char*)d_ws);   // 152MB
    size_t hBytes = ws_size > fixedBytes ? ws_size - fixedBytes : 0;
    int maxM = (int)(hBytes / ((size_t)FFf * sizeof(ushort)));
    if (maxM > BS) maxM = BS;
    if (maxM < 2048) maxM = 2048;        // floor: bounds dispatch explosion
    maxM &= ~127;
    const int nCh    = (BS + maxM - 1) / maxM;
    const int chunkM = ((BS / nCh + 127) / 128) * 128;

    const int wn4 = Ll * FFf * Dd / 4;
    convert_bf16<<<1024, 256, 0, stream>>>(l1_w, w1bf, wn4);
    convert_bf16<<<1024, 256, 0, stream>>>(l2_w, w2bf, wn4);

    encode_kernel<<<2048, 256, 0, stream>>>(src, pe, enc_w, enc_b, fbuf);

    attn_ln_kernel<<<BS / 4, 256, 0, stream>>>(fbuf, xbfA, n1_g, n1_b);

    ushort* xbfCur = xbfA;
    ushort* xbfNxt = xbfB;
    for (int i = 0; i < Ll; ++i) {
        for (int m0 = 0; m0 < BS; m0 += chunkM) {
            int mh = (BS - m0) < chunkM ? (BS - m0) : chunkM;
            gemm_bf16<1, 1><<<dim3(FFf / 128, mh / 128), 256, 0, stream>>>(
                xbfCur + (size_t)m0 * Dd, w1bf + (size_t)i * FFf * Dd,
                l1_b + i * FFf, hbf, mh, FFf, Dd);
            gemm_bf16<0, 0><<<dim3(Dd / 128, mh / 128), 256, 0, stream>>>(
                hbf, w2bf + (size_t)i * Dd * FFf, l2_b + i * Dd,
                fbuf + (size_t)m0 * Dd, mh, Dd, FFf);
        }
        if (i < Ll - 1) {
            fused_tail_attn_kernel<<<BS / 4, 256, 0, stream>>>(
                xbfCur, fbuf,
                n2_g + i * Dd, n2_b + i * Dd,             // LN2 (layer i)
                n1_g + (i + 1) * Dd, n1_b + (i + 1) * Dd, // LN1 (layer i+1)
                xbfNxt);
            ushort* t = xbfCur; xbfCur = xbfNxt; xbfNxt = t;
        } else {
            add_ln_kernel<<<BS / 4, 256, 0, stream>>>(
                xbfCur, fbuf, n2_g + i * Dd, n2_b + i * Dd);
        }
    }

    decode_kernel<<<Bb, 64, 0, stream>>>(fbuf, dec_w, dec_b, out);
}